// Round 18
// baseline (60.947 us; speedup 1.0000x reference)
//
#include <hip/hip_runtime.h>
#include <math.h>

// ---------------------------------------------------------------------------
// WCSA round 18 = round 17 (passing, 59.7us) + spatial LDS-op reduction
// (same-mechanism pair, r16-proven recipes):
//  (1) K/V staging -> global_load_lds width-16, linear LDS + XOR swizzle
//      (inverse-swizzled global source, swizzled fragment reads)
//  (2) P writes packed as uint2 (b64) instead of 2x b32 (bitwise identical)
// All other kernels verbatim r17.
// ---------------------------------------------------------------------------

constexpr int Bb = 4, Nn = 2048, Hh = 4;
constexpr int PROJ_EL = Nn * 256;
constexpr int HEAD_EL = Nn * 64;

typedef __attribute__((ext_vector_type(8))) short short8_t;   // 8 bf16
typedef __attribute__((ext_vector_type(4))) float f32x4;

__device__ __forceinline__ ushort f2bf(float x) {
    union { float f; unsigned u; } v; v.f = x;
    unsigned r = v.u + 0x7fffu + ((v.u >> 16) & 1u);   // RNE
    return (ushort)(r >> 16);
}
__device__ __forceinline__ float bf2f(ushort x) {
    union { unsigned u; float f; } v; v.u = ((unsigned)x) << 16;
    return v.f;
}
// async global->LDS, 16B/lane; LDS dest = wave-uniform base + lane*16
__device__ __forceinline__ void gl_lds16(const ushort* g, ushort* l) {
    __builtin_amdgcn_global_load_lds(
        (const __attribute__((address_space(1))) void*)g,
        (__attribute__((address_space(3))) void*)l, 16, 0, 0);
}

// ---------------- workspace layout (float granularity) ---------------------
constexpr size_t OFF_SB    = 0;
constexpr size_t OFF_SHB   = OFF_SB   + 1024 * 1024;
constexpr size_t OFF_HB    = OFF_SHB  + 1024 * 1024;
constexpr size_t OFF_WQC   = OFF_HB   + 256 * 1024;
constexpr size_t OFF_WCAT  = OFF_WQC  + 32 * 1024;
constexpr size_t OFF_PQC   = OFF_WCAT + 128 * 1024;
constexpr size_t OFF_PQS   = OFF_PQC  + 1024 * 1024;
constexpr size_t OFF_PKC   = OFF_PQS  + 1024 * 1024;
constexpr size_t OFF_PVC   = OFF_PKC  + 1024 * 1024;
constexpr size_t OFF_PKS   = OFF_PVC  + 1024 * 1024;
constexpr size_t OFF_PVST  = OFF_PKS  + 1024 * 1024;
constexpr size_t OFF_PART  = OFF_PVST + 256 * 1024;
constexpr size_t OFF_SCA   = OFF_PART + 512 * 1024;
constexpr size_t OFF_WVS   = OFF_SCA  + 32 * 1024;

// ---------------------------------------------------------------------------
// Convert all needed f32 arrays to bf16 in one pass (unchanged, verified).
// ---------------------------------------------------------------------------
constexpr unsigned SEG0 = 2097152;
constexpr unsigned SEG1 = SEG0 + 2097152;
constexpr unsigned SEG2 = SEG1 + 524288;
constexpr unsigned SEG3 = SEG2 + 65536;
constexpr unsigned SEG4 = SEG3 + 65536;
constexpr unsigned SEG5 = SEG4 + 65536;
constexpr unsigned SEG6 = SEG5 + 65536;
constexpr unsigned SEG7 = SEG6 + 65536;
constexpr unsigned SEG8 = SEG7 + 4096;

__global__ __launch_bounds__(256) void convert_all(
    const float* __restrict__ s, const float* __restrict__ sh,
    const float* __restrict__ h, const float* __restrict__ wqc,
    const float* __restrict__ wqs, const float* __restrict__ wkc,
    const float* __restrict__ wvc, const float* __restrict__ wks,
    const float* __restrict__ wvs,
    ushort* __restrict__ sb, ushort* __restrict__ shb, ushort* __restrict__ hb,
    ushort* __restrict__ wqcb, ushort* __restrict__ wcatb, ushort* __restrict__ wvsb)
{
    unsigned e = (blockIdx.x * 256u + threadIdx.x) * 8u;
    if (e >= SEG8) return;
    const float* src; ushort* dst; unsigned off;
    if      (e < SEG0) { src = s;   dst = sb;             off = e; }
    else if (e < SEG1) { src = sh;  dst = shb;            off = e - SEG0; }
    else if (e < SEG2) { src = h;   dst = hb;             off = e - SEG1; }
    else if (e < SEG3) { src = wqc; dst = wqcb;           off = e - SEG2; }
    else if (e < SEG4) { src = wqs; dst = wcatb;          off = e - SEG3; }
    else if (e < SEG5) { src = wkc; dst = wcatb + 65536;  off = e - SEG4; }
    else if (e < SEG6) { src = wvc; dst = wcatb + 131072; off = e - SEG5; }
    else if (e < SEG7) { src = wks; dst = wcatb + 196608; off = e - SEG6; }
    else               { src = wvs; dst = wvsb;           off = e - SEG7; }
    float4 f0 = *(const float4*)&src[off];
    float4 f1 = *(const float4*)&src[off + 4];
    short8_t o;
    o[0] = f2bf(f0.x); o[1] = f2bf(f0.y); o[2] = f2bf(f0.z); o[3] = f2bf(f0.w);
    o[4] = f2bf(f1.x); o[5] = f2bf(f1.y); o[6] = f2bf(f1.z); o[7] = f2bf(f1.w);
    *(short8_t*)&dst[off] = o;
}

// ---------------------------------------------------------------------------
// GEMM tile body (r16 gload_lds + XOR swizzle, verified).
// ---------------------------------------------------------------------------
__device__ __forceinline__ void gemm_tile_body(
    const ushort* __restrict__ X, const ushort* __restrict__ W,
    ushort* __restrict__ d0, ushort* __restrict__ d1,
    ushort* __restrict__ d2, ushort* __restrict__ d3, int K,
    int m0, int n0, ushort (*Xs)[64], ushort (*Ws)[64])
{
    const int t = threadIdx.x;
    const int w = t >> 6, l = t & 63, c = l & 15, g = l >> 4;
    const int wr = w >> 1, wc = w & 1;
    const int r8 = l >> 3;

    f32x4 acc[4][4] = {};

    for (int k0 = 0; k0 < K; k0 += 64) {
        __syncthreads();
        #pragma unroll
        for (int q = 0; q < 4; ++q) {
            const int rbase = w * 32 + q * 8;
            const int row = rbase + r8;
            const int slot = (l & 7) ^ (row & 7);
            gl_lds16(&X[(size_t)(m0 + row) * K + k0 + slot * 8], &Xs[rbase][0]);
            gl_lds16(&W[(size_t)(n0 + row) * K + k0 + slot * 8], &Ws[rbase][0]);
        }
        __syncthreads();
        #pragma unroll
        for (int ks = 0; ks < 2; ++ks) {
            short8_t af[4], bf[4];
            #pragma unroll
            for (int rt = 0; rt < 4; ++rt) {
                const int R = wr * 64 + rt * 16 + c;
                af[rt] = *(const short8_t*)&Xs[R][(((4 * ks + g) ^ (R & 7)) * 8)];
            }
            #pragma unroll
            for (int ct = 0; ct < 4; ++ct) {
                const int R = wc * 64 + ct * 16 + c;
                bf[ct] = *(const short8_t*)&Ws[R][(((4 * ks + g) ^ (R & 7)) * 8)];
            }
            #pragma unroll
            for (int rt = 0; rt < 4; ++rt)
                #pragma unroll
                for (int ct = 0; ct < 4; ++ct)
                    acc[rt][ct] = __builtin_amdgcn_mfma_f32_16x16x32_bf16(
                        af[rt], bf[ct], acc[rt][ct], 0, 0, 0);
        }
    }

    const int seg = n0 >> 8;
    ushort* dst = seg == 0 ? d0 : seg == 1 ? d1 : seg == 2 ? d2 : d3;
    const int colbase = (n0 & 255) + wc * 64;
    #pragma unroll
    for (int rt = 0; rt < 4; ++rt)
        #pragma unroll
        for (int ct = 0; ct < 4; ++ct)
            #pragma unroll
            for (int r = 0; r < 4; ++r) {
                int mrow = m0 + wr * 64 + rt * 16 + 4 * g + r;
                int col = colbase + ct * 16 + c;
                dst[(size_t)mrow * 256 + col] = f2bf(acc[rt][ct][r]);
            }
}

// ---------------------------------------------------------------------------
// v_s^T tile body (unchanged, verified).
// ---------------------------------------------------------------------------
__device__ __forceinline__ void vs_tile_body(
    const ushort* __restrict__ Wvs, const ushort* __restrict__ Hb,
    ushort* __restrict__ Cvt, int vbid)
{
    const int t = threadIdx.x;
    const int w = t >> 6, l = t & 63, c = l & 15, g = l >> 4;
    const int n0 = vbid * 256 + w * 64;

    f32x4 acc[4][4] = {};
    #pragma unroll
    for (int ks = 0; ks < 2; ++ks) {
        short8_t af[4], bfr[4];
        #pragma unroll
        for (int rt = 0; rt < 4; ++rt)
            af[rt] = *(const short8_t*)&Wvs[(size_t)(rt * 16 + c) * 64 + ks * 32 + 8 * g];
        #pragma unroll
        for (int ct = 0; ct < 4; ++ct)
            bfr[ct] = *(const short8_t*)&Hb[(size_t)(n0 + ct * 16 + c) * 64 + ks * 32 + 8 * g];
        #pragma unroll
        for (int rt = 0; rt < 4; ++rt)
            #pragma unroll
            for (int ct = 0; ct < 4; ++ct)
                acc[rt][ct] = __builtin_amdgcn_mfma_f32_16x16x32_bf16(
                    af[rt], bfr[ct], acc[rt][ct], 0, 0, 0);
    }
    #pragma unroll
    for (int rt = 0; rt < 4; ++rt)
        #pragma unroll
        for (int ct = 0; ct < 4; ++ct)
            #pragma unroll
            for (int r = 0; r < 4; ++r) {
                int cc = rt * 16 + 4 * g + r;
                int m  = n0 + ct * 16 + c;
                int b  = m >> 11, n = m & 2047;
                int L  = n * 64 + cc;
                int hh = L >> 15;
                int k  = (L & 32767) >> 4;
                int d  = L & 15;
                Cvt[(size_t)((b * 4 + hh) * 16 + d) * 2048 + k] = f2bf(acc[rt][ct][r]);
            }
}

// ---------------------------------------------------------------------------
// Fused projection dispatch (r16 routing, verified).
// ---------------------------------------------------------------------------
__global__ __launch_bounds__(256) void proj_all(
    const ushort* __restrict__ shb, const ushort* __restrict__ wcatb,
    ushort* __restrict__ Pqs, ushort* __restrict__ Pkc,
    ushort* __restrict__ Pvc, ushort* __restrict__ Pks,
    const ushort* __restrict__ sb, const ushort* __restrict__ wqcb,
    ushort* __restrict__ Pqc,
    const ushort* __restrict__ wvsb, const ushort* __restrict__ hb,
    ushort* __restrict__ PvsT)
{
    __shared__ ushort Xs[128][64];
    __shared__ ushort Ws[128][64];
    const int bid = blockIdx.x;
    if (bid < 512) {
        gemm_tile_body(shb, wcatb, Pqs, Pkc, Pvc, Pks, 256,
                       (bid >> 3) * 128, (bid & 7) * 128, Xs, Ws);
    } else if (bid < 640) {
        const int r = bid - 512;
        gemm_tile_body(sb, wqcb, Pqc, Pqc, Pqc, Pqc, 256,
                       (r >> 1) * 128, (r & 1) * 128, Xs, Ws);
    } else {
        vs_tile_body(wvsb, hb, PvsT, bid - 640);
    }
}

// ---------------------------------------------------------------------------
// Channel stage 1 via MFMA (r17, verified).
// ---------------------------------------------------------------------------
__global__ __launch_bounds__(256) void chan_qk_mfma(const ushort* __restrict__ Pqc,
                                                    const ushort* __restrict__ Pkc,
                                                    float* __restrict__ part)
{
    const int ch = blockIdx.x, hh = blockIdx.y, b = blockIdx.z;
    const ushort* Q = Pqc + (size_t)b * PROJ_EL + (size_t)hh * HEAD_EL;
    const ushort* Kk = Pkc + (size_t)b * PROJ_EL + (size_t)hh * HEAD_EL;
    __shared__ ushort Qt[64][72];
    __shared__ ushort Kt[64][72];
    const int t = threadIdx.x;
    const int w = t >> 6, l = t & 63, c = l & 15, g = l >> 4;
    const int srow = t & 63;
    const int scol0 = (t >> 6) * 8;

    f32x4 acc[4] = {};

    for (int sub = 0; sub < 4; ++sub) {
        const int r0 = ch * 256 + sub * 64;
        __syncthreads();
        #pragma unroll
        for (int pass = 0; pass < 2; ++pass) {
            const int cbase = scol0 + pass * 32;
            short8_t qv = *(const short8_t*)&Q[(size_t)(r0 + srow) * 64 + cbase];
            short8_t kv = *(const short8_t*)&Kk[(size_t)(r0 + srow) * 64 + cbase];
            #pragma unroll
            for (int j = 0; j < 8; ++j) {
                Qt[cbase + j][srow] = (ushort)qv[j];
                Kt[cbase + j][srow] = (ushort)kv[j];
            }
        }
        __syncthreads();
        #pragma unroll
        for (int ks = 0; ks < 2; ++ks) {
            short8_t af = *(const short8_t*)&Qt[w * 16 + c][ks * 32 + 8 * g];
            #pragma unroll
            for (int ct = 0; ct < 4; ++ct) {
                short8_t bf = *(const short8_t*)&Kt[ct * 16 + c][ks * 32 + 8 * g];
                acc[ct] = __builtin_amdgcn_mfma_f32_16x16x32_bf16(af, bf, acc[ct], 0, 0, 0);
            }
        }
    }

    float* P = part + (((size_t)(b * 4 + hh) * 8 + ch) << 12);
    #pragma unroll
    for (int ct = 0; ct < 4; ++ct)
        #pragma unroll
        for (int r = 0; r < 4; ++r)
            P[(w * 16 + 4 * g + r) * 64 + ct * 16 + c] = acc[ct][r];
}

// ---------------------------------------------------------------------------
// Channel stage 2 (r13 vectorized, verified).
// ---------------------------------------------------------------------------
__global__ __launch_bounds__(256) void chan_softmax(const float* __restrict__ part,
                                                    const float* __restrict__ temp,
                                                    ushort* __restrict__ Sca)
{
    const int bh = blockIdx.x;
    const int hsel = bh & 3;
    const int t = threadIdx.x;
    const int i = t >> 2, q = t & 3;
    const float sT = 0.125f * temp[hsel];

    float v[16];
    #pragma unroll
    for (int jj = 0; jj < 16; ++jj) v[jj] = 0.f;
    #pragma unroll
    for (int cc = 0; cc < 8; ++cc) {
        const float* p = &part[((size_t)bh * 8 + cc) * 4096 + i * 64 + q * 16];
        #pragma unroll
        for (int j4 = 0; j4 < 4; ++j4) {
            float4 f = *(const float4*)&p[j4 * 4];
            v[j4 * 4 + 0] += f.x; v[j4 * 4 + 1] += f.y;
            v[j4 * 4 + 2] += f.z; v[j4 * 4 + 3] += f.w;
        }
    }
    float m = -1e30f;
    #pragma unroll
    for (int jj = 0; jj < 16; ++jj) { v[jj] *= sT; m = fmaxf(m, v[jj]); }
    m = fmaxf(m, __shfl_xor(m, 1, 4));
    m = fmaxf(m, __shfl_xor(m, 2, 4));
    float sum = 0.f;
    #pragma unroll
    for (int jj = 0; jj < 16; ++jj) { v[jj] = __expf(v[jj] - m); sum += v[jj]; }
    sum += __shfl_xor(sum, 1, 4);
    sum += __shfl_xor(sum, 2, 4);
    const float inv = 1.0f / sum;
    ushort* dst = &Sca[((size_t)bh << 12) + i * 64 + q * 16];
    #pragma unroll
    for (int j4 = 0; j4 < 4; ++j4) {
        ushort4 r;
        r.x = f2bf(v[j4 * 4 + 0] * inv); r.y = f2bf(v[j4 * 4 + 1] * inv);
        r.z = f2bf(v[j4 * 4 + 2] * inv); r.w = f2bf(v[j4 * 4 + 3] * inv);
        *(ushort4*)&dst[j4 * 4] = r;
    }
}

// ---------------------------------------------------------------------------
// chan_pv wave-task body (unchanged, verified).
// ---------------------------------------------------------------------------
__device__ __forceinline__ void chan_pv_body(
    const ushort* __restrict__ Sca, const ushort* __restrict__ Pvc,
    float* __restrict__ out, int b, int hh, int nc, int wv, int l)
{
    const int c = l & 15, g = l >> 4;
    const ushort* S = Sca + ((size_t)(b * 4 + hh) << 12);
    const ushort* V = Pvc + (size_t)b * PROJ_EL + (size_t)hh * HEAD_EL;
    const int n0w = nc * 256 + wv * 64;

    f32x4 acc[4][4] = {};
    #pragma unroll
    for (int ks = 0; ks < 2; ++ks) {
        short8_t af[4], bfr[4];
        #pragma unroll
        for (int rt = 0; rt < 4; ++rt)
            af[rt] = *(const short8_t*)&S[(size_t)(rt * 16 + c) * 64 + ks * 32 + 8 * g];
        #pragma unroll
        for (int ct = 0; ct < 4; ++ct)
            bfr[ct] = *(const short8_t*)&V[(size_t)(n0w + ct * 16 + c) * 64 + ks * 32 + 8 * g];
        #pragma unroll
        for (int rt = 0; rt < 4; ++rt)
            #pragma unroll
            for (int ct = 0; ct < 4; ++ct)
                acc[rt][ct] = __builtin_amdgcn_mfma_f32_16x16x32_bf16(
                    af[rt], bfr[ct], acc[rt][ct], 0, 0, 0);
    }

    float* ob = out + (size_t)b * (Nn * 320);
    #pragma unroll
    for (int rt = 0; rt < 4; ++rt)
        #pragma unroll
        for (int ct = 0; ct < 4; ++ct)
            #pragma unroll
            for (int r = 0; r < 4; ++r) {
                int i = rt * 16 + 4 * g + r;
                int nn = n0w + ct * 16 + c;
                int rem = hh * 131072 + i * 2048 + nn;
                ob[(rem >> 8) * 320 + (rem & 255)] = acc[rt][ct][r];
            }
}

// ---------------------------------------------------------------------------
// Fused spatial + chan_pv dispatch, round 18: K/V staged via global_load_lds
// into linear LDS with XOR swizzle (r16 recipe); P writes packed uint2.
// Staging: half sh_=t>>8; wave-within-half wvh=w&3: K 2x 1KB wave-loads
// (rows wvh*16+q*8..+7), V 1x 1KB for wvh<2 (rows wvh*8..+7). Loads issued
// right after the barrier into buf[cur^1]; vmcnt drained by next barrier.
// Fragment reads use slot^(row&7). All math identical to r17.
// ---------------------------------------------------------------------------
__global__ __launch_bounds__(512, 2) void spatial_pv(
    const ushort* __restrict__ Pqs, const ushort* __restrict__ Pks,
    const ushort* __restrict__ PvsT, const float* __restrict__ temp2,
    const ushort* __restrict__ Sca, const ushort* __restrict__ Pvc,
    float* __restrict__ out)
{
    if (blockIdx.x < 64) {
        const int task = blockIdx.x * 8 + (threadIdx.x >> 6);
        const int b2 = task >> 7, rem = task & 127;
        const int hh2 = rem >> 5, rem2 = rem & 31;
        const int nc = rem2 >> 2, wv = rem2 & 3;
        chan_pv_body(Sca, Pvc, out, b2, hh2, nc, wv, threadIdx.x & 63);
        return;
    }

    const int i0 = blockIdx.x - 64;
    const int xcd = i0 & 7, j = i0 >> 3;
    const int hsel = xcd + 8 * (j & 1);
    const int qb = j >> 1;
    const int b = hsel >> 2, hh = hsel & 3;

    const int t = threadIdx.x, w = t >> 6, l = t & 63;
    const int c = l & 15, g = l >> 4;
    const int qg = w >> 1, kh = w & 1;

    __shared__ ushort Kbuf[2][2][64][64];    // [half][dbuf] linear (gload_lds)
    __shared__ ushort Vbuf[2][2][16][64];    // linear
    __shared__ ushort P_lds[8][2][16][72];
    __shared__ float  O_red[8][2][16][16];
    __shared__ float  L_red[8][2][16];

    const ushort* Qh = Pqs + (size_t)b * PROJ_EL + (size_t)hh * HEAD_EL;
    const ushort* Kh = Pks + (size_t)b * PROJ_EL + (size_t)hh * HEAD_EL;
    const ushort* Vt = PvsT + (size_t)((b * 4 + hh) * 16) * 2048;
    const float sT2 = 0.125f * temp2[hh] * 1.44269504f;

    const int q0 = qb * 128 + qg * 32;
    const ushort* qpA = Qh + (size_t)(q0 + c) * 64 + 8 * g;
    const ushort* qpB = qpA + 16 * 64;
    const short8_t qfA0 = *(const short8_t*)qpA;
    const short8_t qfA1 = *(const short8_t*)(qpA + 32);
    const short8_t qfB0 = *(const short8_t*)qpB;
    const short8_t qfB1 = *(const short8_t*)(qpB + 32);

    f32x4 oaccA = {0.f, 0.f, 0.f, 0.f}, oaccB = {0.f, 0.f, 0.f, 0.f};
    float lsumA = 0.f, lsumB = 0.f;
    ushort* PwA = &P_lds[w][0][0][0];
    ushort* PwB = &P_lds[w][1][0][0];

    // staging roles: half sh_ = t>>8; wave-within-half wvh = w&3
    const int sh_ = t >> 8, wvh = w & 3;
    const int r8 = l >> 3;                       // lane's row within 8-row group

    // prologue: stage tile 0 of each half into dbuf 0
    {
        const int kb = (sh_ * 16) * 64;
        #pragma unroll
        for (int q2 = 0; q2 < 2; ++q2) {
            const int rbase = wvh * 16 + q2 * 8;
            const int row = rbase + r8;
            const int slot = (l & 7) ^ (row & 7);
            gl_lds16(&Kh[(size_t)(kb + row) * 64 + slot * 8], &Kbuf[sh_][0][rbase][0]);
        }
        if (wvh < 2) {
            const int rbase = wvh * 8;
            const int row = rbase + r8;
            const int slot = (l & 7) ^ (row & 7);
            gl_lds16(&Vt[(size_t)row * 2048 + kb + slot * 8], &Vbuf[sh_][0][rbase][0]);
        }
    }

    for (int it = 0; it < 16; ++it) {
        const int cur = it & 1;

        __syncthreads();   // drains vmcnt -> tile `it` staged & visible

        // issue next tile's async loads into buf[cur^1] (reads of it done)
        if (it < 15) {
            const int nb = (sh_ * 16 + it + 1) * 64;
            #pragma unroll
            for (int q2 = 0; q2 < 2; ++q2) {
                const int rbase = wvh * 16 + q2 * 8;
                const int row = rbase + r8;
                const int slot = (l & 7) ^ (row & 7);
                gl_lds16(&Kh[(size_t)(nb + row) * 64 + slot * 8],
                         &Kbuf[sh_][cur ^ 1][rbase][0]);
            }
            if (wvh < 2) {
                const int rbase = wvh * 8;
                const int row = rbase + r8;
                const int slot = (l & 7) ^ (row & 7);
                gl_lds16(&Vt[(size_t)row * 2048 + nb + slot * 8],
                         &Vbuf[sh_][cur ^ 1][rbase][0]);
            }
        }

        // QK^T for both subtiles (shared K frags), lane-local softmax
        const int rswz = c & 7;                 // (tc*16+c)&7 == c&7
        #pragma unroll
        for (int tc = 0; tc < 4; ++tc) {
            short8_t kf0 = *(const short8_t*)&Kbuf[kh][cur][tc * 16 + c][(g ^ rswz) * 8];
            short8_t kf1 = *(const short8_t*)&Kbuf[kh][cur][tc * 16 + c][((4 + g) ^ rswz) * 8];
            f32x4 z = {0.f, 0.f, 0.f, 0.f};
            f32x4 sa = __builtin_amdgcn_mfma_f32_16x16x32_bf16(kf0, qfA0, z, 0, 0, 0);
            sa = __builtin_amdgcn_mfma_f32_16x16x32_bf16(kf1, qfA1, sa, 0, 0, 0);
            f32x4 sb2 = __builtin_amdgcn_mfma_f32_16x16x32_bf16(kf0, qfB0, z, 0, 0, 0);
            sb2 = __builtin_amdgcn_mfma_f32_16x16x32_bf16(kf1, qfB1, sb2, 0, 0, 0);

            float a0 = __builtin_amdgcn_exp2f(sa[0] * sT2);
            float a1 = __builtin_amdgcn_exp2f(sa[1] * sT2);
            float a2 = __builtin_amdgcn_exp2f(sa[2] * sT2);
            float a3 = __builtin_amdgcn_exp2f(sa[3] * sT2);
            lsumA += (a0 + a1) + (a2 + a3);
            uint2 pkA;
            asm("v_cvt_pk_bf16_f32 %0, %1, %2" : "=v"(pkA.x) : "v"(a0), "v"(a1));
            asm("v_cvt_pk_bf16_f32 %0, %1, %2" : "=v"(pkA.y) : "v"(a2), "v"(a3));
            *(uint2*)&PwA[(size_t)c * 72 + tc * 16 + 4 * g] = pkA;

            float b0 = __builtin_amdgcn_exp2f(sb2[0] * sT2);
            float b1 = __builtin_amdgcn_exp2f(sb2[1] * sT2);
            float b2 = __builtin_amdgcn_exp2f(sb2[2] * sT2);
            float b3 = __builtin_amdgcn_exp2f(sb2[3] * sT2);
            lsumB += (b0 + b1) + (b2 + b3);
            uint2 pkB;
            asm("v_cvt_pk_bf16_f32 %0, %1, %2" : "=v"(pkB.x) : "v"(b0), "v"(b1));
            asm("v_cvt_pk_bf16_f32 %0, %1, %2" : "=v"(pkB.y) : "v"(b2), "v"(b3));
            *(uint2*)&PwB[(size_t)c * 72 + tc * 16 + 4 * g] = pkB;
        }
        __builtin_amdgcn_sched_barrier(0);
        // PV for both subtiles (V from swizzled linear LDS)
        #pragma unroll
        for (int ks = 0; ks < 2; ++ks) {
            short8_t vf = *(const short8_t*)&Vbuf[kh][cur][c][((4 * ks + g) ^ (c & 7)) * 8];
            short8_t pfA = *(const short8_t*)&PwA[(size_t)c * 72 + ks * 32 + 8 * g];
            oaccA = __builtin_amdgcn_mfma_f32_16x16x32_bf16(vf, pfA, oaccA, 0, 0, 0);
            short8_t pfB = *(const short8_t*)&PwB[(size_t)c * 72 + ks * 32 + 8 * g];
            oaccB = __builtin_amdgcn_mfma_f32_16x16x32_bf16(vf, pfB, oaccB, 0, 0, 0);
        }
    }

    lsumA += __shfl_xor(lsumA, 16);
    lsumA += __shfl_xor(lsumA, 32);
    lsumB += __shfl_xor(lsumB, 16);
    lsumB += __shfl_xor(lsumB, 32);

    *(float4*)&O_red[w][0][c][4 * g] = make_float4(oaccA[0], oaccA[1], oaccA[2], oaccA[3]);
    *(float4*)&O_red[w][1][c][4 * g] = make_float4(oaccB[0], oaccB[1], oaccB[2], oaccB[3]);
    if (g == 0) { L_red[w][0][c] = lsumA; L_red[w][1][c] = lsumB; }
    __syncthreads();

    if (kh == 0) {
        #pragma unroll
        for (int ss = 0; ss < 2; ++ss) {
            float4 o0 = *(const float4*)&O_red[w][ss][c][4 * g];
            float4 o1 = *(const float4*)&O_red[w + 1][ss][c][4 * g];
            float ltot = L_red[w][ss][c] + L_red[w + 1][ss][c];
            const float inv = 1.0f / ltot;
            const int nn = q0 + ss * 16 + c;
            const int n = hh * 512 + (nn >> 2);
            const int cc = 256 + ((nn & 3) << 4) + 4 * g;
            float4 o4 = make_float4((o0.x + o1.x) * inv, (o0.y + o1.y) * inv,
                                    (o0.z + o1.z) * inv, (o0.w + o1.w) * inv);
            *(float4*)&out[((size_t)b * Nn + n) * 320 + cc] = o4;
        }
    }
}

// ---------------------------------------------------------------------------
extern "C" void kernel_launch(void* const* d_in, const int* in_sizes, int n_in,
                              void* d_out, int out_size, void* d_ws, size_t ws_size,
                              hipStream_t stream)
{
    const float* s     = (const float*)d_in[0];
    const float* h     = (const float*)d_in[1];
    const float* sh    = (const float*)d_in[2];
    const float* temp  = (const float*)d_in[3];
    const float* temp2 = (const float*)d_in[4];
    const float* Wq_c  = (const float*)d_in[5];
    const float* Wq_s  = (const float*)d_in[6];
    const float* Wk_c  = (const float*)d_in[7];
    const float* Wv_c  = (const float*)d_in[8];
    const float* Wk_s  = (const float*)d_in[9];
    const float* Wv_s  = (const float*)d_in[10];
    float* out = (float*)d_out;
    float* ws = (float*)d_ws;

    ushort* sb    = (ushort*)(ws + OFF_SB);
    ushort* shb   = (ushort*)(ws + OFF_SHB);
    ushort* hb    = (ushort*)(ws + OFF_HB);
    ushort* wqcb  = (ushort*)(ws + OFF_WQC);
    ushort* wcatb = (ushort*)(ws + OFF_WCAT);
    ushort* wvsb  = (ushort*)(ws + OFF_WVS);
    ushort* Pqc   = (ushort*)(ws + OFF_PQC);
    ushort* Pqs   = (ushort*)(ws + OFF_PQS);
    ushort* Pkc   = (ushort*)(ws + OFF_PKC);
    ushort* Pvc   = (ushort*)(ws + OFF_PVC);
    ushort* Pks   = (ushort*)(ws + OFF_PKS);
    ushort* PvsT  = (ushort*)(ws + OFF_PVST);
    float*  part  = ws + OFF_PART;
    ushort* Sca   = (ushort*)(ws + OFF_SCA);

    const dim3 blk(256);

    // 1) f32 -> bf16 conversions
    convert_all<<<dim3((SEG8 / 8 + 255) / 256), blk, 0, stream>>>(
        s, sh, h, Wq_c, Wq_s, Wk_c, Wv_c, Wk_s, Wv_s,
        sb, shb, hb, wqcb, wcatb, wvsb);

    // 2) all projections in ONE dispatch
    proj_all<<<dim3(672), blk, 0, stream>>>(
        shb, wcatb, Pqs, Pkc, Pvc, Pks, sb, wqcb, Pqc, wvsb, hb, PvsT);

    // 3) channel branch stages 1-2
    chan_qk_mfma<<<dim3(8, 4, 4), blk, 0, stream>>>(Pqc, Pkc, part);
    chan_softmax<<<dim3(16), blk, 0, stream>>>(part, temp, Sca);

    // 4) fused spatial + chan_pv (gload_lds K/V staging, packed P writes)
    spatial_pv<<<dim3(320), dim3(512), 0, stream>>>(
        Pqs, Pks, PvsT, temp2, Sca, Pvc, out);
}

// Round 19
// 60.808 us; speedup vs baseline: 1.0023x; 1.0023x over previous
//
#include <hip/hip_runtime.h>
#include <math.h>

// ---------------------------------------------------------------------------
// WCSA round 19 = round 17 (best, 59.7us; r18's spatial staging change
// REVERTED - regressed +1.2us, LDS-op model falsified) + ONE change:
// chan_qk_mfma 8 -> 16 chunks (grid 256 = 1 block/CU; was 128 = 0.5/CU).
// part buffer grows to 16 partials (r12 layout, fits ws).
// ---------------------------------------------------------------------------

constexpr int Bb = 4, Nn = 2048, Hh = 4;
constexpr int PROJ_EL = Nn * 256;
constexpr int HEAD_EL = Nn * 64;
constexpr int QK_CHUNKS = 16;

typedef __attribute__((ext_vector_type(8))) short short8_t;   // 8 bf16
typedef __attribute__((ext_vector_type(4))) float f32x4;

__device__ __forceinline__ ushort f2bf(float x) {
    union { float f; unsigned u; } v; v.f = x;
    unsigned r = v.u + 0x7fffu + ((v.u >> 16) & 1u);   // RNE
    return (ushort)(r >> 16);
}
__device__ __forceinline__ float bf2f(ushort x) {
    union { unsigned u; float f; } v; v.u = ((unsigned)x) << 16;
    return v.f;
}
// async global->LDS, 16B/lane; LDS dest = wave-uniform base + lane*16
__device__ __forceinline__ void gl_lds16(const ushort* g, ushort* l) {
    __builtin_amdgcn_global_load_lds(
        (const __attribute__((address_space(1))) void*)g,
        (__attribute__((address_space(3))) void*)l, 16, 0, 0);
}

// ---------------- workspace layout (float granularity) ---------------------
constexpr size_t OFF_SB    = 0;
constexpr size_t OFF_SHB   = OFF_SB   + 1024 * 1024;
constexpr size_t OFF_HB    = OFF_SHB  + 1024 * 1024;
constexpr size_t OFF_WQC   = OFF_HB   + 256 * 1024;
constexpr size_t OFF_WCAT  = OFF_WQC  + 32 * 1024;
constexpr size_t OFF_PQC   = OFF_WCAT + 128 * 1024;
constexpr size_t OFF_PQS   = OFF_PQC  + 1024 * 1024;
constexpr size_t OFF_PKC   = OFF_PQS  + 1024 * 1024;
constexpr size_t OFF_PVC   = OFF_PKC  + 1024 * 1024;
constexpr size_t OFF_PKS   = OFF_PVC  + 1024 * 1024;
constexpr size_t OFF_PVST  = OFF_PKS  + 1024 * 1024;
constexpr size_t OFF_PART  = OFF_PVST + 256 * 1024;     // f32 16*16*4096 = 1M
constexpr size_t OFF_SCA   = OFF_PART + 1024 * 1024;
constexpr size_t OFF_WVS   = OFF_SCA  + 32 * 1024;

// ---------------------------------------------------------------------------
// Convert all needed f32 arrays to bf16 in one pass (unchanged, verified).
// ---------------------------------------------------------------------------
constexpr unsigned SEG0 = 2097152;
constexpr unsigned SEG1 = SEG0 + 2097152;
constexpr unsigned SEG2 = SEG1 + 524288;
constexpr unsigned SEG3 = SEG2 + 65536;
constexpr unsigned SEG4 = SEG3 + 65536;
constexpr unsigned SEG5 = SEG4 + 65536;
constexpr unsigned SEG6 = SEG5 + 65536;
constexpr unsigned SEG7 = SEG6 + 65536;
constexpr unsigned SEG8 = SEG7 + 4096;

__global__ __launch_bounds__(256) void convert_all(
    const float* __restrict__ s, const float* __restrict__ sh,
    const float* __restrict__ h, const float* __restrict__ wqc,
    const float* __restrict__ wqs, const float* __restrict__ wkc,
    const float* __restrict__ wvc, const float* __restrict__ wks,
    const float* __restrict__ wvs,
    ushort* __restrict__ sb, ushort* __restrict__ shb, ushort* __restrict__ hb,
    ushort* __restrict__ wqcb, ushort* __restrict__ wcatb, ushort* __restrict__ wvsb)
{
    unsigned e = (blockIdx.x * 256u + threadIdx.x) * 8u;
    if (e >= SEG8) return;
    const float* src; ushort* dst; unsigned off;
    if      (e < SEG0) { src = s;   dst = sb;             off = e; }
    else if (e < SEG1) { src = sh;  dst = shb;            off = e - SEG0; }
    else if (e < SEG2) { src = h;   dst = hb;             off = e - SEG1; }
    else if (e < SEG3) { src = wqc; dst = wqcb;           off = e - SEG2; }
    else if (e < SEG4) { src = wqs; dst = wcatb;          off = e - SEG3; }
    else if (e < SEG5) { src = wkc; dst = wcatb + 65536;  off = e - SEG4; }
    else if (e < SEG6) { src = wvc; dst = wcatb + 131072; off = e - SEG5; }
    else if (e < SEG7) { src = wks; dst = wcatb + 196608; off = e - SEG6; }
    else               { src = wvs; dst = wvsb;           off = e - SEG7; }
    float4 f0 = *(const float4*)&src[off];
    float4 f1 = *(const float4*)&src[off + 4];
    short8_t o;
    o[0] = f2bf(f0.x); o[1] = f2bf(f0.y); o[2] = f2bf(f0.z); o[3] = f2bf(f0.w);
    o[4] = f2bf(f1.x); o[5] = f2bf(f1.y); o[6] = f2bf(f1.z); o[7] = f2bf(f1.w);
    *(short8_t*)&dst[off] = o;
}

// ---------------------------------------------------------------------------
// GEMM tile body (r16 gload_lds + XOR swizzle, verified).
// ---------------------------------------------------------------------------
__device__ __forceinline__ void gemm_tile_body(
    const ushort* __restrict__ X, const ushort* __restrict__ W,
    ushort* __restrict__ d0, ushort* __restrict__ d1,
    ushort* __restrict__ d2, ushort* __restrict__ d3, int K,
    int m0, int n0, ushort (*Xs)[64], ushort (*Ws)[64])
{
    const int t = threadIdx.x;
    const int w = t >> 6, l = t & 63, c = l & 15, g = l >> 4;
    const int wr = w >> 1, wc = w & 1;
    const int r8 = l >> 3;

    f32x4 acc[4][4] = {};

    for (int k0 = 0; k0 < K; k0 += 64) {
        __syncthreads();
        #pragma unroll
        for (int q = 0; q < 4; ++q) {
            const int rbase = w * 32 + q * 8;
            const int row = rbase + r8;
            const int slot = (l & 7) ^ (row & 7);
            gl_lds16(&X[(size_t)(m0 + row) * K + k0 + slot * 8], &Xs[rbase][0]);
            gl_lds16(&W[(size_t)(n0 + row) * K + k0 + slot * 8], &Ws[rbase][0]);
        }
        __syncthreads();
        #pragma unroll
        for (int ks = 0; ks < 2; ++ks) {
            short8_t af[4], bf[4];
            #pragma unroll
            for (int rt = 0; rt < 4; ++rt) {
                const int R = wr * 64 + rt * 16 + c;
                af[rt] = *(const short8_t*)&Xs[R][(((4 * ks + g) ^ (R & 7)) * 8)];
            }
            #pragma unroll
            for (int ct = 0; ct < 4; ++ct) {
                const int R = wc * 64 + ct * 16 + c;
                bf[ct] = *(const short8_t*)&Ws[R][(((4 * ks + g) ^ (R & 7)) * 8)];
            }
            #pragma unroll
            for (int rt = 0; rt < 4; ++rt)
                #pragma unroll
                for (int ct = 0; ct < 4; ++ct)
                    acc[rt][ct] = __builtin_amdgcn_mfma_f32_16x16x32_bf16(
                        af[rt], bf[ct], acc[rt][ct], 0, 0, 0);
        }
    }

    const int seg = n0 >> 8;
    ushort* dst = seg == 0 ? d0 : seg == 1 ? d1 : seg == 2 ? d2 : d3;
    const int colbase = (n0 & 255) + wc * 64;
    #pragma unroll
    for (int rt = 0; rt < 4; ++rt)
        #pragma unroll
        for (int ct = 0; ct < 4; ++ct)
            #pragma unroll
            for (int r = 0; r < 4; ++r) {
                int mrow = m0 + wr * 64 + rt * 16 + 4 * g + r;
                int col = colbase + ct * 16 + c;
                dst[(size_t)mrow * 256 + col] = f2bf(acc[rt][ct][r]);
            }
}

// ---------------------------------------------------------------------------
// v_s^T tile body (unchanged, verified).
// ---------------------------------------------------------------------------
__device__ __forceinline__ void vs_tile_body(
    const ushort* __restrict__ Wvs, const ushort* __restrict__ Hb,
    ushort* __restrict__ Cvt, int vbid)
{
    const int t = threadIdx.x;
    const int w = t >> 6, l = t & 63, c = l & 15, g = l >> 4;
    const int n0 = vbid * 256 + w * 64;

    f32x4 acc[4][4] = {};
    #pragma unroll
    for (int ks = 0; ks < 2; ++ks) {
        short8_t af[4], bfr[4];
        #pragma unroll
        for (int rt = 0; rt < 4; ++rt)
            af[rt] = *(const short8_t*)&Wvs[(size_t)(rt * 16 + c) * 64 + ks * 32 + 8 * g];
        #pragma unroll
        for (int ct = 0; ct < 4; ++ct)
            bfr[ct] = *(const short8_t*)&Hb[(size_t)(n0 + ct * 16 + c) * 64 + ks * 32 + 8 * g];
        #pragma unroll
        for (int rt = 0; rt < 4; ++rt)
            #pragma unroll
            for (int ct = 0; ct < 4; ++ct)
                acc[rt][ct] = __builtin_amdgcn_mfma_f32_16x16x32_bf16(
                    af[rt], bfr[ct], acc[rt][ct], 0, 0, 0);
    }
    #pragma unroll
    for (int rt = 0; rt < 4; ++rt)
        #pragma unroll
        for (int ct = 0; ct < 4; ++ct)
            #pragma unroll
            for (int r = 0; r < 4; ++r) {
                int cc = rt * 16 + 4 * g + r;
                int m  = n0 + ct * 16 + c;
                int b  = m >> 11, n = m & 2047;
                int L  = n * 64 + cc;
                int hh = L >> 15;
                int k  = (L & 32767) >> 4;
                int d  = L & 15;
                Cvt[(size_t)((b * 4 + hh) * 16 + d) * 2048 + k] = f2bf(acc[rt][ct][r]);
            }
}

// ---------------------------------------------------------------------------
// Fused projection dispatch (r16 routing, verified).
// ---------------------------------------------------------------------------
__global__ __launch_bounds__(256) void proj_all(
    const ushort* __restrict__ shb, const ushort* __restrict__ wcatb,
    ushort* __restrict__ Pqs, ushort* __restrict__ Pkc,
    ushort* __restrict__ Pvc, ushort* __restrict__ Pks,
    const ushort* __restrict__ sb, const ushort* __restrict__ wqcb,
    ushort* __restrict__ Pqc,
    const ushort* __restrict__ wvsb, const ushort* __restrict__ hb,
    ushort* __restrict__ PvsT)
{
    __shared__ ushort Xs[128][64];
    __shared__ ushort Ws[128][64];
    const int bid = blockIdx.x;
    if (bid < 512) {
        gemm_tile_body(shb, wcatb, Pqs, Pkc, Pvc, Pks, 256,
                       (bid >> 3) * 128, (bid & 7) * 128, Xs, Ws);
    } else if (bid < 640) {
        const int r = bid - 512;
        gemm_tile_body(sb, wqcb, Pqc, Pqc, Pqc, Pqc, 256,
                       (r >> 1) * 128, (r & 1) * 128, Xs, Ws);
    } else {
        vs_tile_body(wvsb, hb, PvsT, bid - 640);
    }
}

// ---------------------------------------------------------------------------
// Channel stage 1 via MFMA, round 19: 16 chunks of 128 rows (2 subtiles).
// grid (16,4,4) = 256 blocks = 1/CU. Math = r17 pattern, fewer subtiles.
// ---------------------------------------------------------------------------
__global__ __launch_bounds__(256) void chan_qk_mfma(const ushort* __restrict__ Pqc,
                                                    const ushort* __restrict__ Pkc,
                                                    float* __restrict__ part)
{
    const int ch = blockIdx.x, hh = blockIdx.y, b = blockIdx.z;
    const ushort* Q = Pqc + (size_t)b * PROJ_EL + (size_t)hh * HEAD_EL;
    const ushort* Kk = Pkc + (size_t)b * PROJ_EL + (size_t)hh * HEAD_EL;
    __shared__ ushort Qt[64][72];
    __shared__ ushort Kt[64][72];
    const int t = threadIdx.x;
    const int w = t >> 6, l = t & 63, c = l & 15, g = l >> 4;
    const int srow = t & 63;
    const int scol0 = (t >> 6) * 8;

    f32x4 acc[4] = {};

    for (int sub = 0; sub < 2; ++sub) {
        const int r0 = ch * 128 + sub * 64;
        __syncthreads();
        #pragma unroll
        for (int pass = 0; pass < 2; ++pass) {
            const int cbase = scol0 + pass * 32;
            short8_t qv = *(const short8_t*)&Q[(size_t)(r0 + srow) * 64 + cbase];
            short8_t kv = *(const short8_t*)&Kk[(size_t)(r0 + srow) * 64 + cbase];
            #pragma unroll
            for (int j = 0; j < 8; ++j) {
                Qt[cbase + j][srow] = (ushort)qv[j];
                Kt[cbase + j][srow] = (ushort)kv[j];
            }
        }
        __syncthreads();
        #pragma unroll
        for (int ks = 0; ks < 2; ++ks) {
            short8_t af = *(const short8_t*)&Qt[w * 16 + c][ks * 32 + 8 * g];
            #pragma unroll
            for (int ct = 0; ct < 4; ++ct) {
                short8_t bf = *(const short8_t*)&Kt[ct * 16 + c][ks * 32 + 8 * g];
                acc[ct] = __builtin_amdgcn_mfma_f32_16x16x32_bf16(af, bf, acc[ct], 0, 0, 0);
            }
        }
    }

    float* P = part + (((size_t)(b * 4 + hh) * QK_CHUNKS + ch) << 12);
    #pragma unroll
    for (int ct = 0; ct < 4; ++ct)
        #pragma unroll
        for (int r = 0; r < 4; ++r)
            P[(w * 16 + 4 * g + r) * 64 + ct * 16 + c] = acc[ct][r];
}

// ---------------------------------------------------------------------------
// Channel stage 2: reduce 16 partials, scale, softmax (r13 structure).
// ---------------------------------------------------------------------------
__global__ __launch_bounds__(256) void chan_softmax(const float* __restrict__ part,
                                                    const float* __restrict__ temp,
                                                    ushort* __restrict__ Sca)
{
    const int bh = blockIdx.x;
    const int hsel = bh & 3;
    const int t = threadIdx.x;
    const int i = t >> 2, q = t & 3;
    const float sT = 0.125f * temp[hsel];

    float v[16];
    #pragma unroll
    for (int jj = 0; jj < 16; ++jj) v[jj] = 0.f;
    #pragma unroll
    for (int cc = 0; cc < QK_CHUNKS; ++cc) {
        const float* p = &part[((size_t)bh * QK_CHUNKS + cc) * 4096 + i * 64 + q * 16];
        #pragma unroll
        for (int j4 = 0; j4 < 4; ++j4) {
            float4 f = *(const float4*)&p[j4 * 4];
            v[j4 * 4 + 0] += f.x; v[j4 * 4 + 1] += f.y;
            v[j4 * 4 + 2] += f.z; v[j4 * 4 + 3] += f.w;
        }
    }
    float m = -1e30f;
    #pragma unroll
    for (int jj = 0; jj < 16; ++jj) { v[jj] *= sT; m = fmaxf(m, v[jj]); }
    m = fmaxf(m, __shfl_xor(m, 1, 4));
    m = fmaxf(m, __shfl_xor(m, 2, 4));
    float sum = 0.f;
    #pragma unroll
    for (int jj = 0; jj < 16; ++jj) { v[jj] = __expf(v[jj] - m); sum += v[jj]; }
    sum += __shfl_xor(sum, 1, 4);
    sum += __shfl_xor(sum, 2, 4);
    const float inv = 1.0f / sum;
    ushort* dst = &Sca[((size_t)bh << 12) + i * 64 + q * 16];
    #pragma unroll
    for (int j4 = 0; j4 < 4; ++j4) {
        ushort4 r;
        r.x = f2bf(v[j4 * 4 + 0] * inv); r.y = f2bf(v[j4 * 4 + 1] * inv);
        r.z = f2bf(v[j4 * 4 + 2] * inv); r.w = f2bf(v[j4 * 4 + 3] * inv);
        *(ushort4*)&dst[j4 * 4] = r;
    }
}

// ---------------------------------------------------------------------------
// chan_pv wave-task body (unchanged, verified).
// ---------------------------------------------------------------------------
__device__ __forceinline__ void chan_pv_body(
    const ushort* __restrict__ Sca, const ushort* __restrict__ Pvc,
    float* __restrict__ out, int b, int hh, int nc, int wv, int l)
{
    const int c = l & 15, g = l >> 4;
    const ushort* S = Sca + ((size_t)(b * 4 + hh) << 12);
    const ushort* V = Pvc + (size_t)b * PROJ_EL + (size_t)hh * HEAD_EL;
    const int n0w = nc * 256 + wv * 64;

    f32x4 acc[4][4] = {};
    #pragma unroll
    for (int ks = 0; ks < 2; ++ks) {
        short8_t af[4], bfr[4];
        #pragma unroll
        for (int rt = 0; rt < 4; ++rt)
            af[rt] = *(const short8_t*)&S[(size_t)(rt * 16 + c) * 64 + ks * 32 + 8 * g];
        #pragma unroll
        for (int ct = 0; ct < 4; ++ct)
            bfr[ct] = *(const short8_t*)&V[(size_t)(n0w + ct * 16 + c) * 64 + ks * 32 + 8 * g];
        #pragma unroll
        for (int rt = 0; rt < 4; ++rt)
            #pragma unroll
            for (int ct = 0; ct < 4; ++ct)
                acc[rt][ct] = __builtin_amdgcn_mfma_f32_16x16x32_bf16(
                    af[rt], bfr[ct], acc[rt][ct], 0, 0, 0);
    }

    float* ob = out + (size_t)b * (Nn * 320);
    #pragma unroll
    for (int rt = 0; rt < 4; ++rt)
        #pragma unroll
        for (int ct = 0; ct < 4; ++ct)
            #pragma unroll
            for (int r = 0; r < 4; ++r) {
                int i = rt * 16 + 4 * g + r;
                int nn = n0w + ct * 16 + c;
                int rem = hh * 131072 + i * 2048 + nn;
                ob[(rem >> 8) * 320 + (rem & 255)] = acc[rt][ct][r];
            }
}

// ---------------------------------------------------------------------------
// Fused spatial + chan_pv dispatch — r17 VERBATIM (best measured).
// ---------------------------------------------------------------------------
__global__ __launch_bounds__(512, 2) void spatial_pv(
    const ushort* __restrict__ Pqs, const ushort* __restrict__ Pks,
    const ushort* __restrict__ PvsT, const float* __restrict__ temp2,
    const ushort* __restrict__ Sca, const ushort* __restrict__ Pvc,
    float* __restrict__ out)
{
    if (blockIdx.x < 64) {
        const int task = blockIdx.x * 8 + (threadIdx.x >> 6);
        const int b2 = task >> 7, rem = task & 127;
        const int hh2 = rem >> 5, rem2 = rem & 31;
        const int nc = rem2 >> 2, wv = rem2 & 3;
        chan_pv_body(Sca, Pvc, out, b2, hh2, nc, wv, threadIdx.x & 63);
        return;
    }

    const int i0 = blockIdx.x - 64;
    const int xcd = i0 & 7, j = i0 >> 3;
    const int hsel = xcd + 8 * (j & 1);
    const int qb = j >> 1;
    const int b = hsel >> 2, hh = hsel & 3;

    const int t = threadIdx.x, w = t >> 6, l = t & 63;
    const int c = l & 15, g = l >> 4;
    const int qg = w >> 1, kh = w & 1;

    __shared__ ushort Kbuf[2][2][64][72];
    __shared__ ushort Vbuf[2][2][16][72];
    __shared__ ushort P_lds[8][2][16][72];
    __shared__ float  O_red[8][2][16][16];
    __shared__ float  L_red[8][2][16];

    const ushort* Qh = Pqs + (size_t)b * PROJ_EL + (size_t)hh * HEAD_EL;
    const ushort* Kh = Pks + (size_t)b * PROJ_EL + (size_t)hh * HEAD_EL;
    const ushort* Vt = PvsT + (size_t)((b * 4 + hh) * 16) * 2048;
    const float sT2 = 0.125f * temp2[hh] * 1.44269504f;

    const int q0 = qb * 128 + qg * 32;
    const ushort* qpA = Qh + (size_t)(q0 + c) * 64 + 8 * g;
    const ushort* qpB = qpA + 16 * 64;
    const short8_t qfA0 = *(const short8_t*)qpA;
    const short8_t qfA1 = *(const short8_t*)(qpA + 32);
    const short8_t qfB0 = *(const short8_t*)qpB;
    const short8_t qfB1 = *(const short8_t*)(qpB + 32);

    f32x4 oaccA = {0.f, 0.f, 0.f, 0.f}, oaccB = {0.f, 0.f, 0.f, 0.f};
    float lsumA = 0.f, lsumB = 0.f;
    ushort* PwA = &P_lds[w][0][0][0];
    ushort* PwB = &P_lds[w][1][0][0];

    const int sh_ = t >> 8, th = t & 255;
    const int krow = th >> 2, ksub = (th & 3) * 16;
    const int vrow = th >> 4, vcol = (th & 15) * 4;

    {
        const int kb = (sh_ * 16) * 64;
        short8_t k0 = *(const short8_t*)&Kh[(size_t)(kb + krow) * 64 + ksub];
        short8_t k1 = *(const short8_t*)&Kh[(size_t)(kb + krow) * 64 + ksub + 8];
        uint2 v0 = *(const uint2*)&Vt[(size_t)vrow * 2048 + kb + vcol];
        *(short8_t*)&Kbuf[sh_][0][krow][ksub]     = k0;
        *(short8_t*)&Kbuf[sh_][0][krow][ksub + 8] = k1;
        *(uint2*)&Vbuf[sh_][0][vrow][vcol] = v0;
    }

    short8_t kreg0, kreg1; uint2 vreg;
    for (int it = 0; it < 16; ++it) {
        const int cur = it & 1;

        if (it < 15) {
            const int nb = (sh_ * 16 + it + 1) * 64;
            kreg0 = *(const short8_t*)&Kh[(size_t)(nb + krow) * 64 + ksub];
            kreg1 = *(const short8_t*)&Kh[(size_t)(nb + krow) * 64 + ksub + 8];
            vreg = *(const uint2*)&Vt[(size_t)vrow * 2048 + nb + vcol];
        }

        __syncthreads();

        #pragma unroll
        for (int tc = 0; tc < 4; ++tc) {
            short8_t kf0 = *(const short8_t*)&Kbuf[kh][cur][tc * 16 + c][8 * g];
            short8_t kf1 = *(const short8_t*)&Kbuf[kh][cur][tc * 16 + c][32 + 8 * g];
            f32x4 z = {0.f, 0.f, 0.f, 0.f};
            f32x4 sa = __builtin_amdgcn_mfma_f32_16x16x32_bf16(kf0, qfA0, z, 0, 0, 0);
            sa = __builtin_amdgcn_mfma_f32_16x16x32_bf16(kf1, qfA1, sa, 0, 0, 0);
            f32x4 sb2 = __builtin_amdgcn_mfma_f32_16x16x32_bf16(kf0, qfB0, z, 0, 0, 0);
            sb2 = __builtin_amdgcn_mfma_f32_16x16x32_bf16(kf1, qfB1, sb2, 0, 0, 0);

            float a0 = __builtin_amdgcn_exp2f(sa[0] * sT2);
            float a1 = __builtin_amdgcn_exp2f(sa[1] * sT2);
            float a2 = __builtin_amdgcn_exp2f(sa[2] * sT2);
            float a3 = __builtin_amdgcn_exp2f(sa[3] * sT2);
            lsumA += (a0 + a1) + (a2 + a3);
            unsigned ua, ub;
            asm("v_cvt_pk_bf16_f32 %0, %1, %2" : "=v"(ua) : "v"(a0), "v"(a1));
            asm("v_cvt_pk_bf16_f32 %0, %1, %2" : "=v"(ub) : "v"(a2), "v"(a3));
            *(unsigned*)&PwA[(size_t)c * 72 + tc * 16 + 4 * g]     = ua;
            *(unsigned*)&PwA[(size_t)c * 72 + tc * 16 + 4 * g + 2] = ub;

            float b0 = __builtin_amdgcn_exp2f(sb2[0] * sT2);
            float b1 = __builtin_amdgcn_exp2f(sb2[1] * sT2);
            float b2 = __builtin_amdgcn_exp2f(sb2[2] * sT2);
            float b3 = __builtin_amdgcn_exp2f(sb2[3] * sT2);
            lsumB += (b0 + b1) + (b2 + b3);
            unsigned vb0, vb1;
            asm("v_cvt_pk_bf16_f32 %0, %1, %2" : "=v"(vb0) : "v"(b0), "v"(b1));
            asm("v_cvt_pk_bf16_f32 %0, %1, %2" : "=v"(vb1) : "v"(b2), "v"(b3));
            *(unsigned*)&PwB[(size_t)c * 72 + tc * 16 + 4 * g]     = vb0;
            *(unsigned*)&PwB[(size_t)c * 72 + tc * 16 + 4 * g + 2] = vb1;
        }
        __builtin_amdgcn_sched_barrier(0);
        #pragma unroll
        for (int ks = 0; ks < 2; ++ks) {
            short8_t vf = *(const short8_t*)&Vbuf[kh][cur][c][ks * 32 + 8 * g];
            short8_t pfA = *(const short8_t*)&PwA[(size_t)c * 72 + ks * 32 + 8 * g];
            oaccA = __builtin_amdgcn_mfma_f32_16x16x32_bf16(vf, pfA, oaccA, 0, 0, 0);
            short8_t pfB = *(const short8_t*)&PwB[(size_t)c * 72 + ks * 32 + 8 * g];
            oaccB = __builtin_amdgcn_mfma_f32_16x16x32_bf16(vf, pfB, oaccB, 0, 0, 0);
        }

        if (it < 15) {
            *(short8_t*)&Kbuf[sh_][cur ^ 1][krow][ksub]     = kreg0;
            *(short8_t*)&Kbuf[sh_][cur ^ 1][krow][ksub + 8] = kreg1;
            *(uint2*)&Vbuf[sh_][cur ^ 1][vrow][vcol] = vreg;
        }
    }

    lsumA += __shfl_xor(lsumA, 16);
    lsumA += __shfl_xor(lsumA, 32);
    lsumB += __shfl_xor(lsumB, 16);
    lsumB += __shfl_xor(lsumB, 32);

    *(float4*)&O_red[w][0][c][4 * g] = make_float4(oaccA[0], oaccA[1], oaccA[2], oaccA[3]);
    *(float4*)&O_red[w][1][c][4 * g] = make_float4(oaccB[0], oaccB[1], oaccB[2], oaccB[3]);
    if (g == 0) { L_red[w][0][c] = lsumA; L_red[w][1][c] = lsumB; }
    __syncthreads();

    if (kh == 0) {
        #pragma unroll
        for (int ss = 0; ss < 2; ++ss) {
            float4 o0 = *(const float4*)&O_red[w][ss][c][4 * g];
            float4 o1 = *(const float4*)&O_red[w + 1][ss][c][4 * g];
            float ltot = L_red[w][ss][c] + L_red[w + 1][ss][c];
            const float inv = 1.0f / ltot;
            const int nn = q0 + ss * 16 + c;
            const int n = hh * 512 + (nn >> 2);
            const int cc = 256 + ((nn & 3) << 4) + 4 * g;
            float4 o4 = make_float4((o0.x + o1.x) * inv, (o0.y + o1.y) * inv,
                                    (o0.z + o1.z) * inv, (o0.w + o1.w) * inv);
            *(float4*)&out[((size_t)b * Nn + n) * 320 + cc] = o4;
        }
    }
}

// ---------------------------------------------------------------------------
extern "C" void kernel_launch(void* const* d_in, const int* in_sizes, int n_in,
                              void* d_out, int out_size, void* d_ws, size_t ws_size,
                              hipStream_t stream)
{
    const float* s     = (const float*)d_in[0];
    const float* h     = (const float*)d_in[1];
    const float* sh    = (const float*)d_in[2];
    const float* temp  = (const float*)d_in[3];
    const float* temp2 = (const float*)d_in[4];
    const float* Wq_c  = (const float*)d_in[5];
    const float* Wq_s  = (const float*)d_in[6];
    const float* Wk_c  = (const float*)d_in[7];
    const float* Wv_c  = (const float*)d_in[8];
    const float* Wk_s  = (const float*)d_in[9];
    const float* Wv_s  = (const float*)d_in[10];
    float* out = (float*)d_out;
    float* ws = (float*)d_ws;

    ushort* sb    = (ushort*)(ws + OFF_SB);
    ushort* shb   = (ushort*)(ws + OFF_SHB);
    ushort* hb    = (ushort*)(ws + OFF_HB);
    ushort* wqcb  = (ushort*)(ws + OFF_WQC);
    ushort* wcatb = (ushort*)(ws + OFF_WCAT);
    ushort* wvsb  = (ushort*)(ws + OFF_WVS);
    ushort* Pqc   = (ushort*)(ws + OFF_PQC);
    ushort* Pqs   = (ushort*)(ws + OFF_PQS);
    ushort* Pkc   = (ushort*)(ws + OFF_PKC);
    ushort* Pvc   = (ushort*)(ws + OFF_PVC);
    ushort* Pks   = (ushort*)(ws + OFF_PKS);
    ushort* PvsT  = (ushort*)(ws + OFF_PVST);
    float*  part  = ws + OFF_PART;
    ushort* Sca   = (ushort*)(ws + OFF_SCA);

    const dim3 blk(256);

    // 1) f32 -> bf16 conversions
    convert_all<<<dim3((SEG8 / 8 + 255) / 256), blk, 0, stream>>>(
        s, sh, h, Wq_c, Wq_s, Wk_c, Wv_c, Wk_s, Wv_s,
        sb, shb, hb, wqcb, wcatb, wvsb);

    // 2) all projections in ONE dispatch
    proj_all<<<dim3(672), blk, 0, stream>>>(
        shb, wcatb, Pqs, Pkc, Pvc, Pks, sb, wqcb, Pqc, wvsb, hb, PvsT);

    // 3) channel branch stages 1-2 (16 chunks)
    chan_qk_mfma<<<dim3(QK_CHUNKS, 4, 4), blk, 0, stream>>>(Pqc, Pkc, part);
    chan_softmax<<<dim3(16), blk, 0, stream>>>(part, temp, Sca);

    // 4) fused spatial + chan_pv (r17 spatial, best measured)
    spatial_pv<<<dim3(320), dim3(512), 0, stream>>>(
        Pqs, Pks, PvsT, temp2, Sca, Pvc, out);
}

// Round 20
// 59.622 us; speedup vs baseline: 1.0222x; 1.0199x over previous
//
#include <hip/hip_runtime.h>
#include <math.h>

// ---------------------------------------------------------------------------
// WCSA round 20 = round 17 VERBATIM (best measured: 59.7us, absmax 1.41e-3).
// r18 (spatial gload_lds staging) and r19 (16-chunk chan_qk) both regressed
// and are reverted. Final configuration:
//  - convert_all: one-pass f32->bf16 (HBM-bound, ~6.6 TB/s)
//  - proj_all: fused 672-block MFMA GEMM dispatch, global_load_lds width-16
//    staging with rule-21 XOR swizzle
//  - chan_qk_mfma: 8-chunk MFMA QK^T partials
//  - chan_softmax: vectorized 256-thread softmax
//  - spatial_pv: fused spatial attention (swapped QK^T, lane-local softmax,
//    no max-subtraction, split-KV x2, reg-staged LDS double-buffer, XCD
//    swizzle) + chan_pv wave-tasks
// ---------------------------------------------------------------------------

constexpr int Bb = 4, Nn = 2048, Hh = 4;
constexpr int PROJ_EL = Nn * 256;
constexpr int HEAD_EL = Nn * 64;

typedef __attribute__((ext_vector_type(8))) short short8_t;   // 8 bf16
typedef __attribute__((ext_vector_type(4))) float f32x4;

__device__ __forceinline__ ushort f2bf(float x) {
    union { float f; unsigned u; } v; v.f = x;
    unsigned r = v.u + 0x7fffu + ((v.u >> 16) & 1u);   // RNE
    return (ushort)(r >> 16);
}
__device__ __forceinline__ float bf2f(ushort x) {
    union { unsigned u; float f; } v; v.u = ((unsigned)x) << 16;
    return v.f;
}
// async global->LDS, 16B/lane; LDS dest = wave-uniform base + lane*16
__device__ __forceinline__ void gl_lds16(const ushort* g, ushort* l) {
    __builtin_amdgcn_global_load_lds(
        (const __attribute__((address_space(1))) void*)g,
        (__attribute__((address_space(3))) void*)l, 16, 0, 0);
}

// ---------------- workspace layout (float granularity) ---------------------
constexpr size_t OFF_SB    = 0;
constexpr size_t OFF_SHB   = OFF_SB   + 1024 * 1024;
constexpr size_t OFF_HB    = OFF_SHB  + 1024 * 1024;
constexpr size_t OFF_WQC   = OFF_HB   + 256 * 1024;
constexpr size_t OFF_WCAT  = OFF_WQC  + 32 * 1024;
constexpr size_t OFF_PQC   = OFF_WCAT + 128 * 1024;
constexpr size_t OFF_PQS   = OFF_PQC  + 1024 * 1024;
constexpr size_t OFF_PKC   = OFF_PQS  + 1024 * 1024;
constexpr size_t OFF_PVC   = OFF_PKC  + 1024 * 1024;
constexpr size_t OFF_PKS   = OFF_PVC  + 1024 * 1024;
constexpr size_t OFF_PVST  = OFF_PKS  + 1024 * 1024;
constexpr size_t OFF_PART  = OFF_PVST + 256 * 1024;
constexpr size_t OFF_SCA   = OFF_PART + 512 * 1024;
constexpr size_t OFF_WVS   = OFF_SCA  + 32 * 1024;

// ---------------------------------------------------------------------------
// Convert all needed f32 arrays to bf16 in one pass (verified).
// ---------------------------------------------------------------------------
constexpr unsigned SEG0 = 2097152;
constexpr unsigned SEG1 = SEG0 + 2097152;
constexpr unsigned SEG2 = SEG1 + 524288;
constexpr unsigned SEG3 = SEG2 + 65536;
constexpr unsigned SEG4 = SEG3 + 65536;
constexpr unsigned SEG5 = SEG4 + 65536;
constexpr unsigned SEG6 = SEG5 + 65536;
constexpr unsigned SEG7 = SEG6 + 65536;
constexpr unsigned SEG8 = SEG7 + 4096;

__global__ __launch_bounds__(256) void convert_all(
    const float* __restrict__ s, const float* __restrict__ sh,
    const float* __restrict__ h, const float* __restrict__ wqc,
    const float* __restrict__ wqs, const float* __restrict__ wkc,
    const float* __restrict__ wvc, const float* __restrict__ wks,
    const float* __restrict__ wvs,
    ushort* __restrict__ sb, ushort* __restrict__ shb, ushort* __restrict__ hb,
    ushort* __restrict__ wqcb, ushort* __restrict__ wcatb, ushort* __restrict__ wvsb)
{
    unsigned e = (blockIdx.x * 256u + threadIdx.x) * 8u;
    if (e >= SEG8) return;
    const float* src; ushort* dst; unsigned off;
    if      (e < SEG0) { src = s;   dst = sb;             off = e; }
    else if (e < SEG1) { src = sh;  dst = shb;            off = e - SEG0; }
    else if (e < SEG2) { src = h;   dst = hb;             off = e - SEG1; }
    else if (e < SEG3) { src = wqc; dst = wqcb;           off = e - SEG2; }
    else if (e < SEG4) { src = wqs; dst = wcatb;          off = e - SEG3; }
    else if (e < SEG5) { src = wkc; dst = wcatb + 65536;  off = e - SEG4; }
    else if (e < SEG6) { src = wvc; dst = wcatb + 131072; off = e - SEG5; }
    else if (e < SEG7) { src = wks; dst = wcatb + 196608; off = e - SEG6; }
    else               { src = wvs; dst = wvsb;           off = e - SEG7; }
    float4 f0 = *(const float4*)&src[off];
    float4 f1 = *(const float4*)&src[off + 4];
    short8_t o;
    o[0] = f2bf(f0.x); o[1] = f2bf(f0.y); o[2] = f2bf(f0.z); o[3] = f2bf(f0.w);
    o[4] = f2bf(f1.x); o[5] = f2bf(f1.y); o[6] = f2bf(f1.z); o[7] = f2bf(f1.w);
    *(short8_t*)&dst[off] = o;
}

// ---------------------------------------------------------------------------
// GEMM tile body (gload_lds + XOR swizzle, verified r16).
// ---------------------------------------------------------------------------
__device__ __forceinline__ void gemm_tile_body(
    const ushort* __restrict__ X, const ushort* __restrict__ W,
    ushort* __restrict__ d0, ushort* __restrict__ d1,
    ushort* __restrict__ d2, ushort* __restrict__ d3, int K,
    int m0, int n0, ushort (*Xs)[64], ushort (*Ws)[64])
{
    const int t = threadIdx.x;
    const int w = t >> 6, l = t & 63, c = l & 15, g = l >> 4;
    const int wr = w >> 1, wc = w & 1;
    const int r8 = l >> 3;

    f32x4 acc[4][4] = {};

    for (int k0 = 0; k0 < K; k0 += 64) {
        __syncthreads();
        #pragma unroll
        for (int q = 0; q < 4; ++q) {
            const int rbase = w * 32 + q * 8;
            const int row = rbase + r8;
            const int slot = (l & 7) ^ (row & 7);
            gl_lds16(&X[(size_t)(m0 + row) * K + k0 + slot * 8], &Xs[rbase][0]);
            gl_lds16(&W[(size_t)(n0 + row) * K + k0 + slot * 8], &Ws[rbase][0]);
        }
        __syncthreads();
        #pragma unroll
        for (int ks = 0; ks < 2; ++ks) {
            short8_t af[4], bf[4];
            #pragma unroll
            for (int rt = 0; rt < 4; ++rt) {
                const int R = wr * 64 + rt * 16 + c;
                af[rt] = *(const short8_t*)&Xs[R][(((4 * ks + g) ^ (R & 7)) * 8)];
            }
            #pragma unroll
            for (int ct = 0; ct < 4; ++ct) {
                const int R = wc * 64 + ct * 16 + c;
                bf[ct] = *(const short8_t*)&Ws[R][(((4 * ks + g) ^ (R & 7)) * 8)];
            }
            #pragma unroll
            for (int rt = 0; rt < 4; ++rt)
                #pragma unroll
                for (int ct = 0; ct < 4; ++ct)
                    acc[rt][ct] = __builtin_amdgcn_mfma_f32_16x16x32_bf16(
                        af[rt], bf[ct], acc[rt][ct], 0, 0, 0);
        }
    }

    const int seg = n0 >> 8;
    ushort* dst = seg == 0 ? d0 : seg == 1 ? d1 : seg == 2 ? d2 : d3;
    const int colbase = (n0 & 255) + wc * 64;
    #pragma unroll
    for (int rt = 0; rt < 4; ++rt)
        #pragma unroll
        for (int ct = 0; ct < 4; ++ct)
            #pragma unroll
            for (int r = 0; r < 4; ++r) {
                int mrow = m0 + wr * 64 + rt * 16 + 4 * g + r;
                int col = colbase + ct * 16 + c;
                dst[(size_t)mrow * 256 + col] = f2bf(acc[rt][ct][r]);
            }
}

// ---------------------------------------------------------------------------
// v_s^T tile body (verified r6).
// ---------------------------------------------------------------------------
__device__ __forceinline__ void vs_tile_body(
    const ushort* __restrict__ Wvs, const ushort* __restrict__ Hb,
    ushort* __restrict__ Cvt, int vbid)
{
    const int t = threadIdx.x;
    const int w = t >> 6, l = t & 63, c = l & 15, g = l >> 4;
    const int n0 = vbid * 256 + w * 64;

    f32x4 acc[4][4] = {};
    #pragma unroll
    for (int ks = 0; ks < 2; ++ks) {
        short8_t af[4], bfr[4];
        #pragma unroll
        for (int rt = 0; rt < 4; ++rt)
            af[rt] = *(const short8_t*)&Wvs[(size_t)(rt * 16 + c) * 64 + ks * 32 + 8 * g];
        #pragma unroll
        for (int ct = 0; ct < 4; ++ct)
            bfr[ct] = *(const short8_t*)&Hb[(size_t)(n0 + ct * 16 + c) * 64 + ks * 32 + 8 * g];
        #pragma unroll
        for (int rt = 0; rt < 4; ++rt)
            #pragma unroll
            for (int ct = 0; ct < 4; ++ct)
                acc[rt][ct] = __builtin_amdgcn_mfma_f32_16x16x32_bf16(
                    af[rt], bfr[ct], acc[rt][ct], 0, 0, 0);
    }
    #pragma unroll
    for (int rt = 0; rt < 4; ++rt)
        #pragma unroll
        for (int ct = 0; ct < 4; ++ct)
            #pragma unroll
            for (int r = 0; r < 4; ++r) {
                int cc = rt * 16 + 4 * g + r;
                int m  = n0 + ct * 16 + c;
                int b  = m >> 11, n = m & 2047;
                int L  = n * 64 + cc;
                int hh = L >> 15;
                int k  = (L & 32767) >> 4;
                int d  = L & 15;
                Cvt[(size_t)((b * 4 + hh) * 16 + d) * 2048 + k] = f2bf(acc[rt][ct][r]);
            }
}

// ---------------------------------------------------------------------------
// Fused projection dispatch: 672 blocks x 256 thr.
// ---------------------------------------------------------------------------
__global__ __launch_bounds__(256) void proj_all(
    const ushort* __restrict__ shb, const ushort* __restrict__ wcatb,
    ushort* __restrict__ Pqs, ushort* __restrict__ Pkc,
    ushort* __restrict__ Pvc, ushort* __restrict__ Pks,
    const ushort* __restrict__ sb, const ushort* __restrict__ wqcb,
    ushort* __restrict__ Pqc,
    const ushort* __restrict__ wvsb, const ushort* __restrict__ hb,
    ushort* __restrict__ PvsT)
{
    __shared__ ushort Xs[128][64];
    __shared__ ushort Ws[128][64];
    const int bid = blockIdx.x;
    if (bid < 512) {
        gemm_tile_body(shb, wcatb, Pqs, Pkc, Pvc, Pks, 256,
                       (bid >> 3) * 128, (bid & 7) * 128, Xs, Ws);
    } else if (bid < 640) {
        const int r = bid - 512;
        gemm_tile_body(sb, wqcb, Pqc, Pqc, Pqc, Pqc, 256,
                       (r >> 1) * 128, (r & 1) * 128, Xs, Ws);
    } else {
        vs_tile_body(wvsb, hb, PvsT, bid - 640);
    }
}

// ---------------------------------------------------------------------------
// Channel stage 1 via MFMA (verified r17): 8 chunks of 256 rows.
// ---------------------------------------------------------------------------
__global__ __launch_bounds__(256) void chan_qk_mfma(const ushort* __restrict__ Pqc,
                                                    const ushort* __restrict__ Pkc,
                                                    float* __restrict__ part)
{
    const int ch = blockIdx.x, hh = blockIdx.y, b = blockIdx.z;
    const ushort* Q = Pqc + (size_t)b * PROJ_EL + (size_t)hh * HEAD_EL;
    const ushort* Kk = Pkc + (size_t)b * PROJ_EL + (size_t)hh * HEAD_EL;
    __shared__ ushort Qt[64][72];
    __shared__ ushort Kt[64][72];
    const int t = threadIdx.x;
    const int w = t >> 6, l = t & 63, c = l & 15, g = l >> 4;
    const int srow = t & 63;
    const int scol0 = (t >> 6) * 8;

    f32x4 acc[4] = {};

    for (int sub = 0; sub < 4; ++sub) {
        const int r0 = ch * 256 + sub * 64;
        __syncthreads();
        #pragma unroll
        for (int pass = 0; pass < 2; ++pass) {
            const int cbase = scol0 + pass * 32;
            short8_t qv = *(const short8_t*)&Q[(size_t)(r0 + srow) * 64 + cbase];
            short8_t kv = *(const short8_t*)&Kk[(size_t)(r0 + srow) * 64 + cbase];
            #pragma unroll
            for (int j = 0; j < 8; ++j) {
                Qt[cbase + j][srow] = (ushort)qv[j];
                Kt[cbase + j][srow] = (ushort)kv[j];
            }
        }
        __syncthreads();
        #pragma unroll
        for (int ks = 0; ks < 2; ++ks) {
            short8_t af = *(const short8_t*)&Qt[w * 16 + c][ks * 32 + 8 * g];
            #pragma unroll
            for (int ct = 0; ct < 4; ++ct) {
                short8_t bf = *(const short8_t*)&Kt[ct * 16 + c][ks * 32 + 8 * g];
                acc[ct] = __builtin_amdgcn_mfma_f32_16x16x32_bf16(af, bf, acc[ct], 0, 0, 0);
            }
        }
    }

    float* P = part + (((size_t)(b * 4 + hh) * 8 + ch) << 12);
    #pragma unroll
    for (int ct = 0; ct < 4; ++ct)
        #pragma unroll
        for (int r = 0; r < 4; ++r)
            P[(w * 16 + 4 * g + r) * 64 + ct * 16 + c] = acc[ct][r];
}

// ---------------------------------------------------------------------------
// Channel stage 2 (vectorized, verified r13).
// ---------------------------------------------------------------------------
__global__ __launch_bounds__(256) void chan_softmax(const float* __restrict__ part,
                                                    const float* __restrict__ temp,
                                                    ushort* __restrict__ Sca)
{
    const int bh = blockIdx.x;
    const int hsel = bh & 3;
    const int t = threadIdx.x;
    const int i = t >> 2, q = t & 3;
    const float sT = 0.125f * temp[hsel];

    float v[16];
    #pragma unroll
    for (int jj = 0; jj < 16; ++jj) v[jj] = 0.f;
    #pragma unroll
    for (int cc = 0; cc < 8; ++cc) {
        const float* p = &part[((size_t)bh * 8 + cc) * 4096 + i * 64 + q * 16];
        #pragma unroll
        for (int j4 = 0; j4 < 4; ++j4) {
            float4 f = *(const float4*)&p[j4 * 4];
            v[j4 * 4 + 0] += f.x; v[j4 * 4 + 1] += f.y;
            v[j4 * 4 + 2] += f.z; v[j4 * 4 + 3] += f.w;
        }
    }
    float m = -1e30f;
    #pragma unroll
    for (int jj = 0; jj < 16; ++jj) { v[jj] *= sT; m = fmaxf(m, v[jj]); }
    m = fmaxf(m, __shfl_xor(m, 1, 4));
    m = fmaxf(m, __shfl_xor(m, 2, 4));
    float sum = 0.f;
    #pragma unroll
    for (int jj = 0; jj < 16; ++jj) { v[jj] = __expf(v[jj] - m); sum += v[jj]; }
    sum += __shfl_xor(sum, 1, 4);
    sum += __shfl_xor(sum, 2, 4);
    const float inv = 1.0f / sum;
    ushort* dst = &Sca[((size_t)bh << 12) + i * 64 + q * 16];
    #pragma unroll
    for (int j4 = 0; j4 < 4; ++j4) {
        ushort4 r;
        r.x = f2bf(v[j4 * 4 + 0] * inv); r.y = f2bf(v[j4 * 4 + 1] * inv);
        r.z = f2bf(v[j4 * 4 + 2] * inv); r.w = f2bf(v[j4 * 4 + 3] * inv);
        *(ushort4*)&dst[j4 * 4] = r;
    }
}

// ---------------------------------------------------------------------------
// chan_pv wave-task body (verified r3).
// ---------------------------------------------------------------------------
__device__ __forceinline__ void chan_pv_body(
    const ushort* __restrict__ Sca, const ushort* __restrict__ Pvc,
    float* __restrict__ out, int b, int hh, int nc, int wv, int l)
{
    const int c = l & 15, g = l >> 4;
    const ushort* S = Sca + ((size_t)(b * 4 + hh) << 12);
    const ushort* V = Pvc + (size_t)b * PROJ_EL + (size_t)hh * HEAD_EL;
    const int n0w = nc * 256 + wv * 64;

    f32x4 acc[4][4] = {};
    #pragma unroll
    for (int ks = 0; ks < 2; ++ks) {
        short8_t af[4], bfr[4];
        #pragma unroll
        for (int rt = 0; rt < 4; ++rt)
            af[rt] = *(const short8_t*)&S[(size_t)(rt * 16 + c) * 64 + ks * 32 + 8 * g];
        #pragma unroll
        for (int ct = 0; ct < 4; ++ct)
            bfr[ct] = *(const short8_t*)&V[(size_t)(n0w + ct * 16 + c) * 64 + ks * 32 + 8 * g];
        #pragma unroll
        for (int rt = 0; rt < 4; ++rt)
            #pragma unroll
            for (int ct = 0; ct < 4; ++ct)
                acc[rt][ct] = __builtin_amdgcn_mfma_f32_16x16x32_bf16(
                    af[rt], bfr[ct], acc[rt][ct], 0, 0, 0);
    }

    float* ob = out + (size_t)b * (Nn * 320);
    #pragma unroll
    for (int rt = 0; rt < 4; ++rt)
        #pragma unroll
        for (int ct = 0; ct < 4; ++ct)
            #pragma unroll
            for (int r = 0; r < 4; ++r) {
                int i = rt * 16 + 4 * g + r;
                int nn = n0w + ct * 16 + c;
                int rem = hh * 131072 + i * 2048 + nn;
                ob[(rem >> 8) * 320 + (rem & 255)] = acc[rt][ct][r];
            }
}

// ---------------------------------------------------------------------------
// Fused spatial + chan_pv dispatch (verified r15-r17).
// ---------------------------------------------------------------------------
__global__ __launch_bounds__(512, 2) void spatial_pv(
    const ushort* __restrict__ Pqs, const ushort* __restrict__ Pks,
    const ushort* __restrict__ PvsT, const float* __restrict__ temp2,
    const ushort* __restrict__ Sca, const ushort* __restrict__ Pvc,
    float* __restrict__ out)
{
    if (blockIdx.x < 64) {
        const int task = blockIdx.x * 8 + (threadIdx.x >> 6);
        const int b2 = task >> 7, rem = task & 127;
        const int hh2 = rem >> 5, rem2 = rem & 31;
        const int nc = rem2 >> 2, wv = rem2 & 3;
        chan_pv_body(Sca, Pvc, out, b2, hh2, nc, wv, threadIdx.x & 63);
        return;
    }

    const int i0 = blockIdx.x - 64;
    const int xcd = i0 & 7, j = i0 >> 3;
    const int hsel = xcd + 8 * (j & 1);
    const int qb = j >> 1;
    const int b = hsel >> 2, hh = hsel & 3;

    const int t = threadIdx.x, w = t >> 6, l = t & 63;
    const int c = l & 15, g = l >> 4;
    const int qg = w >> 1, kh = w & 1;

    __shared__ ushort Kbuf[2][2][64][72];
    __shared__ ushort Vbuf[2][2][16][72];
    __shared__ ushort P_lds[8][2][16][72];
    __shared__ float  O_red[8][2][16][16];
    __shared__ float  L_red[8][2][16];

    const ushort* Qh = Pqs + (size_t)b * PROJ_EL + (size_t)hh * HEAD_EL;
    const ushort* Kh = Pks + (size_t)b * PROJ_EL + (size_t)hh * HEAD_EL;
    const ushort* Vt = PvsT + (size_t)((b * 4 + hh) * 16) * 2048;
    const float sT2 = 0.125f * temp2[hh] * 1.44269504f;

    const int q0 = qb * 128 + qg * 32;
    const ushort* qpA = Qh + (size_t)(q0 + c) * 64 + 8 * g;
    const ushort* qpB = qpA + 16 * 64;
    const short8_t qfA0 = *(const short8_t*)qpA;
    const short8_t qfA1 = *(const short8_t*)(qpA + 32);
    const short8_t qfB0 = *(const short8_t*)qpB;
    const short8_t qfB1 = *(const short8_t*)(qpB + 32);

    f32x4 oaccA = {0.f, 0.f, 0.f, 0.f}, oaccB = {0.f, 0.f, 0.f, 0.f};
    float lsumA = 0.f, lsumB = 0.f;
    ushort* PwA = &P_lds[w][0][0][0];
    ushort* PwB = &P_lds[w][1][0][0];

    const int sh_ = t >> 8, th = t & 255;
    const int krow = th >> 2, ksub = (th & 3) * 16;
    const int vrow = th >> 4, vcol = (th & 15) * 4;

    {
        const int kb = (sh_ * 16) * 64;
        short8_t k0 = *(const short8_t*)&Kh[(size_t)(kb + krow) * 64 + ksub];
        short8_t k1 = *(const short8_t*)&Kh[(size_t)(kb + krow) * 64 + ksub + 8];
        uint2 v0 = *(const uint2*)&Vt[(size_t)vrow * 2048 + kb + vcol];
        *(short8_t*)&Kbuf[sh_][0][krow][ksub]     = k0;
        *(short8_t*)&Kbuf[sh_][0][krow][ksub + 8] = k1;
        *(uint2*)&Vbuf[sh_][0][vrow][vcol] = v0;
    }

    short8_t kreg0, kreg1; uint2 vreg;
    for (int it = 0; it < 16; ++it) {
        const int cur = it & 1;

        if (it < 15) {
            const int nb = (sh_ * 16 + it + 1) * 64;
            kreg0 = *(const short8_t*)&Kh[(size_t)(nb + krow) * 64 + ksub];
            kreg1 = *(const short8_t*)&Kh[(size_t)(nb + krow) * 64 + ksub + 8];
            vreg = *(const uint2*)&Vt[(size_t)vrow * 2048 + nb + vcol];
        }

        __syncthreads();

        #pragma unroll
        for (int tc = 0; tc < 4; ++tc) {
            short8_t kf0 = *(const short8_t*)&Kbuf[kh][cur][tc * 16 + c][8 * g];
            short8_t kf1 = *(const short8_t*)&Kbuf[kh][cur][tc * 16 + c][32 + 8 * g];
            f32x4 z = {0.f, 0.f, 0.f, 0.f};
            f32x4 sa = __builtin_amdgcn_mfma_f32_16x16x32_bf16(kf0, qfA0, z, 0, 0, 0);
            sa = __builtin_amdgcn_mfma_f32_16x16x32_bf16(kf1, qfA1, sa, 0, 0, 0);
            f32x4 sb2 = __builtin_amdgcn_mfma_f32_16x16x32_bf16(kf0, qfB0, z, 0, 0, 0);
            sb2 = __builtin_amdgcn_mfma_f32_16x16x32_bf16(kf1, qfB1, sb2, 0, 0, 0);

            float a0 = __builtin_amdgcn_exp2f(sa[0] * sT2);
            float a1 = __builtin_amdgcn_exp2f(sa[1] * sT2);
            float a2 = __builtin_amdgcn_exp2f(sa[2] * sT2);
            float a3 = __builtin_amdgcn_exp2f(sa[3] * sT2);
            lsumA += (a0 + a1) + (a2 + a3);
            unsigned ua, ub;
            asm("v_cvt_pk_bf16_f32 %0, %1, %2" : "=v"(ua) : "v"(a0), "v"(a1));
            asm("v_cvt_pk_bf16_f32 %0, %1, %2" : "=v"(ub) : "v"(a2), "v"(a3));
            *(unsigned*)&PwA[(size_t)c * 72 + tc * 16 + 4 * g]     = ua;
            *(unsigned*)&PwA[(size_t)c * 72 + tc * 16 + 4 * g + 2] = ub;

            float b0 = __builtin_amdgcn_exp2f(sb2[0] * sT2);
            float b1 = __builtin_amdgcn_exp2f(sb2[1] * sT2);
            float b2 = __builtin_amdgcn_exp2f(sb2[2] * sT2);
            float b3 = __builtin_amdgcn_exp2f(sb2[3] * sT2);
            lsumB += (b0 + b1) + (b2 + b3);
            unsigned vb0, vb1;
            asm("v_cvt_pk_bf16_f32 %0, %1, %2" : "=v"(vb0) : "v"(b0), "v"(b1));
            asm("v_cvt_pk_bf16_f32 %0, %1, %2" : "=v"(vb1) : "v"(b2), "v"(b3));
            *(unsigned*)&PwB[(size_t)c * 72 + tc * 16 + 4 * g]     = vb0;
            *(unsigned*)&PwB[(size_t)c * 72 + tc * 16 + 4 * g + 2] = vb1;
        }
        __builtin_amdgcn_sched_barrier(0);
        #pragma unroll
        for (int ks = 0; ks < 2; ++ks) {
            short8_t vf = *(const short8_t*)&Vbuf[kh][cur][c][ks * 32 + 8 * g];
            short8_t pfA = *(const short8_t*)&PwA[(size_t)c * 72 + ks * 32 + 8 * g];
            oaccA = __builtin_amdgcn_mfma_f32_16x16x32_bf16(vf, pfA, oaccA, 0, 0, 0);
            short8_t pfB = *(const short8_t*)&PwB[(size_t)c * 72 + ks * 32 + 8 * g];
            oaccB = __builtin_amdgcn_mfma_f32_16x16x32_bf16(vf, pfB, oaccB, 0, 0, 0);
        }

        if (it < 15) {
            *(short8_t*)&Kbuf[sh_][cur ^ 1][krow][ksub]     = kreg0;
            *(short8_t*)&Kbuf[sh_][cur ^ 1][krow][ksub + 8] = kreg1;
            *(uint2*)&Vbuf[sh_][cur ^ 1][vrow][vcol] = vreg;
        }
    }

    lsumA += __shfl_xor(lsumA, 16);
    lsumA += __shfl_xor(lsumA, 32);
    lsumB += __shfl_xor(lsumB, 16);
    lsumB += __shfl_xor(lsumB, 32);

    *(float4*)&O_red[w][0][c][4 * g] = make_float4(oaccA[0], oaccA[1], oaccA[2], oaccA[3]);
    *(float4*)&O_red[w][1][c][4 * g] = make_float4(oaccB[0], oaccB[1], oaccB[2], oaccB[3]);
    if (g == 0) { L_red[w][0][c] = lsumA; L_red[w][1][c] = lsumB; }
    __syncthreads();

    if (kh == 0) {
        #pragma unroll
        for (int ss = 0; ss < 2; ++ss) {
            float4 o0 = *(const float4*)&O_red[w][ss][c][4 * g];
            float4 o1 = *(const float4*)&O_red[w + 1][ss][c][4 * g];
            float ltot = L_red[w][ss][c] + L_red[w + 1][ss][c];
            const float inv = 1.0f / ltot;
            const int nn = q0 + ss * 16 + c;
            const int n = hh * 512 + (nn >> 2);
            const int cc = 256 + ((nn & 3) << 4) + 4 * g;
            float4 o4 = make_float4((o0.x + o1.x) * inv, (o0.y + o1.y) * inv,
                                    (o0.z + o1.z) * inv, (o0.w + o1.w) * inv);
            *(float4*)&out[((size_t)b * Nn + n) * 320 + cc] = o4;
        }
    }
}

// ---------------------------------------------------------------------------
extern "C" void kernel_launch(void* const* d_in, const int* in_sizes, int n_in,
                              void* d_out, int out_size, void* d_ws, size_t ws_size,
                              hipStream_t stream)
{
    const float* s     = (const float*)d_in[0];
    const float* h     = (const float*)d_in[1];
    const float* sh    = (const float*)d_in[2];
    const float* temp  = (const float*)d_in[3];
    const float* temp2 = (const float*)d_in[4];
    const float* Wq_c  = (const float*)d_in[5];
    const float* Wq_s  = (const float*)d_in[6];
    const float* Wk_c  = (const float*)d_in[7];
    const float* Wv_c  = (const float*)d_in[8];
    const float* Wk_s  = (const float*)d_in[9];
    const float* Wv_s  = (const float*)d_in[10];
    float* out = (float*)d_out;
    float* ws = (float*)d_ws;

    ushort* sb    = (ushort*)(ws + OFF_SB);
    ushort* shb   = (ushort*)(ws + OFF_SHB);
    ushort* hb    = (ushort*)(ws + OFF_HB);
    ushort* wqcb  = (ushort*)(ws + OFF_WQC);
    ushort* wcatb = (ushort*)(ws + OFF_WCAT);
    ushort* wvsb  = (ushort*)(ws + OFF_WVS);
    ushort* Pqc   = (ushort*)(ws + OFF_PQC);
    ushort* Pqs   = (ushort*)(ws + OFF_PQS);
    ushort* Pkc   = (ushort*)(ws + OFF_PKC);
    ushort* Pvc   = (ushort*)(ws + OFF_PVC);
    ushort* Pks   = (ushort*)(ws + OFF_PKS);
    ushort* PvsT  = (ushort*)(ws + OFF_PVST);
    float*  part  = ws + OFF_PART;
    ushort* Sca   = (ushort*)(ws + OFF_SCA);

    const dim3 blk(256);

    // 1) f32 -> bf16 conversions
    convert_all<<<dim3((SEG8 / 8 + 255) / 256), blk, 0, stream>>>(
        s, sh, h, Wq_c, Wq_s, Wk_c, Wv_c, Wk_s, Wv_s,
        sb, shb, hb, wqcb, wcatb, wvsb);

    // 2) all projections in ONE dispatch
    proj_all<<<dim3(672), blk, 0, stream>>>(
        shb, wcatb, Pqs, Pkc, Pvc, Pks, sb, wqcb, Pqc, wvsb, hb, PvsT);

    // 3) channel branch stages 1-2
    chan_qk_mfma<<<dim3(8, 4, 4), blk, 0, stream>>>(Pqc, Pkc, part);
    chan_softmax<<<dim3(16), blk, 0, stream>>>(part, temp, Sca);

    // 4) fused spatial + chan_pv
    spatial_pv<<<dim3(320), dim3(512), 0, stream>>>(
        Pqs, Pks, PvsT, temp2, Sca, Pvc, out);
}